// Round 5
// baseline (60645.752 us; speedup 1.0000x reference)
//
#include <hip/hip_runtime.h>
#include <hip/hip_cooperative_groups.h>

#define B_ 64
#define T_ 512
#define D_ 1024
#define H_ 1024
#define NG_ 4096   // 4*H
#define NBLK 256   // blocks in the persistent recurrence kernel

// ---------------- h transpose helpers ----------------
__global__ __launch_bounds__(256) void k_trans_h_fwd(const float* __restrict__ h,
                                                     float* __restrict__ hT) {
  int idx = blockIdx.x * 256 + threadIdx.x;  // idx = k*64 + b
  int b = idx & 63;
  int k = idx >> 6;
  hT[idx] = h[b * H_ + k];
}

__global__ __launch_bounds__(256) void k_trans_h_back(const float* __restrict__ hT,
                                                      float* __restrict__ h) {
  int idx = blockIdx.x * 256 + threadIdx.x;  // idx = b*1024 + k
  int k = idx & (H_ - 1);
  int b = idx >> 10;
  h[idx] = hT[k * 64 + b];
}

// ---------------- Gx = x@Wi + bias, batched over a time chunk ----------------
// __launch_bounds__(512, 2): VGPR budget 256 — acc[4][4] + pipelined loads must
// stay in registers (at (512) default the compiler capped VGPRs at 32 -> spills).
__global__ __launch_bounds__(512, 2) void k_gx(
    const float* __restrict__ x,     // [64][512][1024]
    const float* __restrict__ Wi,    // [1024][4096]
    const float* __restrict__ bias,  // [4096]
    float* __restrict__ gx,          // [Tc][256][64][16]
    int t0) {
  __shared__ float xt[64 * 65];
  __shared__ float red[8 * 64 * 17];

  const int tid = threadIdx.x;
  const int lane = tid & 63;
  const int w = tid >> 6;
  const int hbase = blockIdx.x * 4;
  const int t = t0 + blockIdx.y;

  float acc[4][4];
#pragma unroll
  for (int c = 0; c < 4; ++c)
#pragma unroll
    for (int g = 0; g < 4; ++g) acc[c][g] = 0.f;

  for (int kt = 0; kt < 16; ++kt) {
    __syncthreads();
#pragma unroll
    for (int p = 0; p < 8; ++p) {
      int r = p * 8 + (tid >> 6);
      int dd = tid & 63;
      xt[dd * 65 + r] = x[(size_t)r * (T_ * D_) + (size_t)t * D_ + kt * 64 + dd];
    }
    __syncthreads();
    const int kkbase = w * 8;
#pragma unroll
    for (int kk = kkbase; kk < kkbase + 8; ++kk) {
      const int k = kt * 64 + kk;
      const float xv = xt[kk * 65 + lane];
#pragma unroll
      for (int g = 0; g < 4; ++g) {
        const float4 wi = *(const float4*)(Wi + (size_t)k * NG_ + g * H_ + hbase);
        acc[0][g] = fmaf(xv, wi.x, acc[0][g]);
        acc[1][g] = fmaf(xv, wi.y, acc[1][g]);
        acc[2][g] = fmaf(xv, wi.z, acc[2][g]);
        acc[3][g] = fmaf(xv, wi.w, acc[3][g]);
      }
    }
  }

#pragma unroll
  for (int c = 0; c < 4; ++c)
#pragma unroll
    for (int g = 0; g < 4; ++g) red[(w * 64 + lane) * 17 + c * 4 + g] = acc[c][g];
  __syncthreads();

  if (tid < 256) {
    const int b = tid >> 2;
    const int c = tid & 3;
    const int h = hbase + c;
    float4 v;
    float* vp = &v.x;
#pragma unroll
    for (int g = 0; g < 4; ++g) {
      float s = bias[g * H_ + h];
#pragma unroll
      for (int ww = 0; ww < 8; ++ww) s += red[(ww * 64 + b) * 17 + c * 4 + g];
      vp[g] = s;
    }
    *(float4*)(gx + ((size_t)(blockIdx.y * 256 + blockIdx.x) * 64 + b) * 16 + c * 4) = v;
  }
}

// ---------------- persistent recurrence with lightweight grid barrier ----------------
// Grid: 256 blocks x 512 threads, 1 block/CU (98KB dynamic LDS).
// __launch_bounds__(512, 2): LDS already caps at 1 block/CU = 2 waves/SIMD, so
// request the full 256-VGPR budget instead of the default 32 (which spilled).
__global__ __launch_bounds__(512, 2) void k_recur(
    const float* __restrict__ Wh,     // [1024][4096]
    const float* __restrict__ gx,     // [tc][256][64][16] (bias folded)
    float* __restrict__ hA,           // hT ping [1024][64]
    float* __restrict__ hB,           // hT pong [1024][64]
    float* __restrict__ c_state,      // [64][1024] in-place
    float* __restrict__ ys,           // [64][512][1024]
    unsigned* __restrict__ bar,       // monotonic barrier counter (zeroed per launch)
    int t0, int tc) {
  extern __shared__ float smem[];
  float* wlds = smem;           // 16384 floats = 64 KB
  float* red = smem + 16384;    // 8704 floats = 34 KB

  const int tid = threadIdx.x;
  const int lane = tid & 63;
  const int w = tid >> 6;
  const int hbase = blockIdx.x * 4;

  // stage this block's Wh slice once: wlds[k*16 + g*4 + c]
  for (int idx = tid; idx < 4096; idx += 512) {
    const int k = idx >> 2;
    const int g = idx & 3;
    const float4 v = *(const float4*)(Wh + (size_t)k * NG_ + g * H_ + hbase);
    *(float4*)(wlds + k * 16 + g * 4) = v;
  }
  __syncthreads();

  for (int tt = 0; tt < tc; ++tt) {
    const int t = t0 + tt;
    const float* hin = (t & 1) ? hB : hA;
    float* hout = (t & 1) ? hA : hB;

    float acc[4][4];
#pragma unroll
    for (int c = 0; c < 4; ++c)
#pragma unroll
      for (int g = 0; g < 4; ++g) acc[c][g] = 0.f;

    const int k0 = w * 128;
#pragma unroll 8
    for (int k = k0; k < k0 + 128; ++k) {
      const float hv = hin[k * 64 + lane];
      const float4 w0 = *(const float4*)(wlds + k * 16);
      const float4 w1 = *(const float4*)(wlds + k * 16 + 4);
      const float4 w2 = *(const float4*)(wlds + k * 16 + 8);
      const float4 w3 = *(const float4*)(wlds + k * 16 + 12);
      acc[0][0] = fmaf(hv, w0.x, acc[0][0]);
      acc[1][0] = fmaf(hv, w0.y, acc[1][0]);
      acc[2][0] = fmaf(hv, w0.z, acc[2][0]);
      acc[3][0] = fmaf(hv, w0.w, acc[3][0]);
      acc[0][1] = fmaf(hv, w1.x, acc[0][1]);
      acc[1][1] = fmaf(hv, w1.y, acc[1][1]);
      acc[2][1] = fmaf(hv, w1.z, acc[2][1]);
      acc[3][1] = fmaf(hv, w1.w, acc[3][1]);
      acc[0][2] = fmaf(hv, w2.x, acc[0][2]);
      acc[1][2] = fmaf(hv, w2.y, acc[1][2]);
      acc[2][2] = fmaf(hv, w2.z, acc[2][2]);
      acc[3][2] = fmaf(hv, w2.w, acc[3][2]);
      acc[0][3] = fmaf(hv, w3.x, acc[0][3]);
      acc[1][3] = fmaf(hv, w3.y, acc[1][3]);
      acc[2][3] = fmaf(hv, w3.z, acc[2][3]);
      acc[3][3] = fmaf(hv, w3.w, acc[3][3]);
    }

#pragma unroll
    for (int c = 0; c < 4; ++c)
#pragma unroll
      for (int g = 0; g < 4; ++g) red[(w * 64 + lane) * 17 + c * 4 + g] = acc[c][g];
    __syncthreads();

    if (tid < 256) {
      const int b = tid >> 2;
      const int c = tid & 3;
      const int h = hbase + c;
      const float4 gxv =
          *(const float4*)(gx + ((size_t)(tt * 256 + blockIdx.x) * 64 + b) * 16 + c * 4);
      const float* gp = &gxv.x;
      float v[4];
#pragma unroll
      for (int g = 0; g < 4; ++g) {
        float s = gp[g];
#pragma unroll
        for (int ww = 0; ww < 8; ++ww) s += red[(ww * 64 + b) * 17 + c * 4 + g];
        v[g] = s;
      }
      const float cold = c_state[b * H_ + h];
      const float si = 1.f / (1.f + expf(-v[0]));
      const float sf = 1.f / (1.f + expf(-v[1]));
      const float gt = tanhf(v[2]);
      const float so = 1.f / (1.f + expf(-v[3]));
      const float cn = sf * cold + si * gt;
      const float hn = so * tanhf(cn);
      c_state[b * H_ + h] = cn;
      hout[h * 64 + b] = hn;
      ys[(size_t)b * (T_ * H_) + (size_t)t * H_ + h] = hn;
    }

    // ---- lightweight grid barrier ----
    __syncthreads();
    if (tid == 0) {
      __threadfence();
      __hip_atomic_fetch_add(bar, 1u, __ATOMIC_ACQ_REL, __HIP_MEMORY_SCOPE_AGENT);
      const unsigned target = (unsigned)NBLK * (unsigned)(t + 1);
      while (__hip_atomic_load(bar, __ATOMIC_ACQUIRE, __HIP_MEMORY_SCOPE_AGENT) < target) {
        __builtin_amdgcn_s_sleep(2);
      }
      __threadfence();
    }
    __syncthreads();
  }
}

// ---------------- fallback: fused step (tiny ws) ----------------
__global__ __launch_bounds__(512, 2) void k_lstm_step_fused(
    const float* __restrict__ xsrc, const float* __restrict__ Wi,
    const float* __restrict__ Wh, const float* __restrict__ bias,
    const float* __restrict__ hT_in, float* __restrict__ hT_out,
    float* __restrict__ c_state, float* __restrict__ ys_t) {
  __shared__ float red[8 * 64 * 17];
  const int tid = threadIdx.x;
  const int lane = tid & 63;
  const int w = tid >> 6;
  const int hbase = blockIdx.x * 4;
  float acc[4][4];
#pragma unroll
  for (int c = 0; c < 4; ++c)
#pragma unroll
    for (int g = 0; g < 4; ++g) acc[c][g] = 0.f;
  const int k0 = w * 128;
#pragma unroll 2
  for (int k = k0; k < k0 + 128; ++k) {
    const float hv = hT_in[k * 64 + lane];
    const float xv = xsrc[(size_t)lane * (T_ * D_) + k];
#pragma unroll
    for (int g = 0; g < 4; ++g) {
      const float4 wh = *(const float4*)(Wh + (size_t)k * NG_ + g * H_ + hbase);
      const float4 wi = *(const float4*)(Wi + (size_t)k * NG_ + g * H_ + hbase);
      acc[0][g] = fmaf(hv, wh.x, acc[0][g]);
      acc[1][g] = fmaf(hv, wh.y, acc[1][g]);
      acc[2][g] = fmaf(hv, wh.z, acc[2][g]);
      acc[3][g] = fmaf(hv, wh.w, acc[3][g]);
      acc[0][g] = fmaf(xv, wi.x, acc[0][g]);
      acc[1][g] = fmaf(xv, wi.y, acc[1][g]);
      acc[2][g] = fmaf(xv, wi.z, acc[2][g]);
      acc[3][g] = fmaf(xv, wi.w, acc[3][g]);
    }
  }
#pragma unroll
  for (int c = 0; c < 4; ++c)
#pragma unroll
    for (int g = 0; g < 4; ++g) red[(w * 64 + lane) * 17 + c * 4 + g] = acc[c][g];
  __syncthreads();
  if (tid < 256) {
    const int b = tid >> 2;
    const int c = tid & 3;
    const int h = hbase + c;
    float v[4];
#pragma unroll
    for (int g = 0; g < 4; ++g) {
      float s = bias[g * H_ + h];
#pragma unroll
      for (int ww = 0; ww < 8; ++ww) s += red[(ww * 64 + b) * 17 + c * 4 + g];
      v[g] = s;
    }
    const float cold = c_state[b * H_ + h];
    const float si = 1.f / (1.f + expf(-v[0]));
    const float sf = 1.f / (1.f + expf(-v[1]));
    const float gt = tanhf(v[2]);
    const float so = 1.f / (1.f + expf(-v[3]));
    const float cn = sf * cold + si * gt;
    const float hn = so * tanhf(cn);
    c_state[b * H_ + h] = cn;
    hT_out[h * 64 + b] = hn;
    ys_t[(size_t)b * (T_ * H_) + h] = hn;
  }
}

extern "C" void kernel_launch(void* const* d_in, const int* in_sizes, int n_in,
                              void* d_out, int out_size, void* d_ws, size_t ws_size,
                              hipStream_t stream) {
  const float* c0   = (const float*)d_in[0];
  const float* h0   = (const float*)d_in[1];
  const float* x    = (const float*)d_in[2];
  const float* Wi   = (const float*)d_in[3];
  const float* Wh   = (const float*)d_in[4];
  const float* bias = (const float*)d_in[5];

  float* out     = (float*)d_out;
  float* c_state = out;
  float* h_final = out + B_ * H_;
  float* ys      = out + 2 * B_ * H_;

  const size_t hbytes = (size_t)B_ * H_ * sizeof(float);
  unsigned* bar = (unsigned*)d_ws;                         // 1 KB reserved
  float* hA = (float*)((char*)d_ws + 1024);
  float* hB = hA + B_ * H_;
  float* gxbuf = hB + B_ * H_;

  const size_t slice = (size_t)256 * 64 * 16 * sizeof(float);  // 1 MB per t
  size_t fixed = 1024 + 2 * hbytes;
  size_t avail = (ws_size > fixed) ? ws_size - fixed : 0;
  int Tc = (int)(avail / slice);
  if (Tc > T_) Tc = T_;

  hipMemsetAsync(bar, 0, 1024, stream);   // reset barrier counter every launch
  hipMemcpyAsync(c_state, c0, hbytes, hipMemcpyDeviceToDevice, stream);
  k_trans_h_fwd<<<B_ * H_ / 256, 256, 0, stream>>>(h0, hA);

  const unsigned smem_recur = (16384 + 8704) * sizeof(float);  // 100352 B

  if (Tc >= 1) {
    for (int t0 = 0; t0 < T_; t0 += Tc) {
      const int tc = (T_ - t0 < Tc) ? (T_ - t0) : Tc;
      dim3 gg(256, tc);
      k_gx<<<gg, 512, 0, stream>>>(x, Wi, bias, gxbuf, t0);
      int t0v = t0, tcv = tc;
      void* args[] = {(void*)&Wh,  (void*)&gxbuf,   (void*)&hA,
                      (void*)&hB,  (void*)&c_state, (void*)&ys,
                      (void*)&bar, (void*)&t0v,     (void*)&tcv};
      hipLaunchCooperativeKernel((void*)k_recur, dim3(NBLK), dim3(512), args,
                                 smem_recur, stream);
    }
  } else {
    for (int t = 0; t < T_; ++t) {
      const float* hin = (t & 1) ? hB : hA;
      float* hout      = (t & 1) ? hA : hB;
      k_lstm_step_fused<<<256, 512, 0, stream>>>(
          x + (size_t)t * D_, Wi, Wh, bias, hin, hout, c_state,
          ys + (size_t)t * H_);
    }
  }
  k_trans_h_back<<<B_ * H_ / 256, 256, 0, stream>>>(hA, h_final);
}

// Round 6
// 35612.445 us; speedup vs baseline: 1.7029x; 1.7029x over previous
//
#include <hip/hip_runtime.h>
#include <hip/hip_cooperative_groups.h>

#define B_ 64
#define T_ 512
#define D_ 1024
#define H_ 1024
#define NG_ 4096   // 4*H
#define NBLK 256   // blocks in the persistent recurrence kernel

// ---------------- h transpose helpers ----------------
__global__ __launch_bounds__(256) void k_trans_h_fwd(const float* __restrict__ h,
                                                     float* __restrict__ hT) {
  int idx = blockIdx.x * 256 + threadIdx.x;  // idx = k*64 + b
  int b = idx & 63;
  int k = idx >> 6;
  hT[idx] = h[b * H_ + k];
}

__global__ __launch_bounds__(256) void k_trans_h_back(const float* __restrict__ hT,
                                                      float* __restrict__ h) {
  int idx = blockIdx.x * 256 + threadIdx.x;  // idx = b*1024 + k
  int k = idx & (H_ - 1);
  int b = idx >> 10;
  h[idx] = hT[k * 64 + b];
}

// 16 FMAs into acc[4][4] from one scalar value V and 4 float4 weight quads
#define FMA16(V, W0, W1, W2, W3)                \
  acc[0][0] = fmaf((V), (W0).x, acc[0][0]);     \
  acc[1][0] = fmaf((V), (W0).y, acc[1][0]);     \
  acc[2][0] = fmaf((V), (W0).z, acc[2][0]);     \
  acc[3][0] = fmaf((V), (W0).w, acc[3][0]);     \
  acc[0][1] = fmaf((V), (W1).x, acc[0][1]);     \
  acc[1][1] = fmaf((V), (W1).y, acc[1][1]);     \
  acc[2][1] = fmaf((V), (W1).z, acc[2][1]);     \
  acc[3][1] = fmaf((V), (W1).w, acc[3][1]);     \
  acc[0][2] = fmaf((V), (W2).x, acc[0][2]);     \
  acc[1][2] = fmaf((V), (W2).y, acc[1][2]);     \
  acc[2][2] = fmaf((V), (W2).z, acc[2][2]);     \
  acc[3][2] = fmaf((V), (W2).w, acc[3][2]);     \
  acc[0][3] = fmaf((V), (W3).x, acc[0][3]);     \
  acc[1][3] = fmaf((V), (W3).y, acc[1][3]);     \
  acc[2][3] = fmaf((V), (W3).z, acc[3][3] * 0.f + acc[2][3]); \
  acc[3][3] = fmaf((V), (W3).w, acc[3][3]);

// NOTE: the odd-looking acc[2][3] line above would be a bug; use clean macro:
#undef FMA16
#define FMA16(V, W0, W1, W2, W3)                \
  acc[0][0] = fmaf((V), (W0).x, acc[0][0]);     \
  acc[1][0] = fmaf((V), (W0).y, acc[1][0]);     \
  acc[2][0] = fmaf((V), (W0).z, acc[2][0]);     \
  acc[3][0] = fmaf((V), (W0).w, acc[3][0]);     \
  acc[0][1] = fmaf((V), (W1).x, acc[0][1]);     \
  acc[1][1] = fmaf((V), (W1).y, acc[1][1]);     \
  acc[2][1] = fmaf((V), (W1).z, acc[2][1]);     \
  acc[3][1] = fmaf((V), (W1).w, acc[3][1]);     \
  acc[0][2] = fmaf((V), (W2).x, acc[0][2]);     \
  acc[1][2] = fmaf((V), (W2).y, acc[1][2]);     \
  acc[2][2] = fmaf((V), (W2).z, acc[2][2]);     \
  acc[3][2] = fmaf((V), (W2).w, acc[3][2]);     \
  acc[0][3] = fmaf((V), (W3).x, acc[0][3]);     \
  acc[1][3] = fmaf((V), (W3).y, acc[1][3]);     \
  acc[2][3] = fmaf((V), (W3).z, acc[2][3]);     \
  acc[3][3] = fmaf((V), (W3).w, acc[3][3]);

// ---------------- Gx = x@Wi + bias ----------------
// Grid: (tc, 256). Block 512 thr. LDS 34.8KB (xt double-buffer union red)
// -> up to 4 blocks/CU; consecutive blocks share the same Wi slice (L1/L2 reuse).
// Per slab: T14 stage-split (loads issued early, ds_write after prior barrier).
#define GXLOAD(S)                                                   \
  { pf0 = *(const float4*)(xrow + (S) * 64 + c4);                   \
    pf1 = *(const float4*)(xrow + (S) * 64 + c4 + 32); }
#define GXWRITE(BUF)                                                \
  { float* q = (BUF) + (tid >> 3) * 65 + c4;                        \
    q[0] = pf0.x; q[1] = pf0.y; q[2] = pf0.z; q[3] = pf0.w;         \
    q[32] = pf1.x; q[33] = pf1.y; q[34] = pf1.z; q[35] = pf1.w; }
#define GXCMP(BUF)                                                  \
  _Pragma("unroll") for (int j = 0; j < 8; ++j) {                   \
    const int k = s * 64 + (w << 3) + j;                            \
    const float xv = (BUF)[lane * 65 + (w << 3) + j];               \
    const float* wp = Wi + (size_t)k * NG_ + hbase;                 \
    const float4 w0 = *(const float4*)(wp);                         \
    const float4 w1 = *(const float4*)(wp + H_);                    \
    const float4 w2 = *(const float4*)(wp + 2 * H_);                \
    const float4 w3 = *(const float4*)(wp + 3 * H_);                \
    FMA16(xv, w0, w1, w2, w3)                                       \
  }

__global__ __launch_bounds__(512, 2) void k_gx(
    const float* __restrict__ x,     // [64][512][1024]
    const float* __restrict__ Wi,    // [1024][4096]
    const float* __restrict__ bias,  // [4096]
    float* __restrict__ gx,          // [Tc][256][64][16]
    int t0) {
  __shared__ float smem[8704];       // xt0[4160] | xt1[4160]  (union: red[8704])
  float* xt0 = smem;
  float* xt1 = smem + 4160;
  float* red = smem;

  const int tid = threadIdx.x;
  const int lane = tid & 63;
  const int w = tid >> 6;
  const int hbase = blockIdx.y * 4;
  const int t = t0 + blockIdx.x;

  const float* xrow = x + (size_t)(tid >> 3) * (T_ * D_) + (size_t)t * D_;
  const int c4 = (tid & 7) * 4;

  float acc[4][4];
#pragma unroll
  for (int c = 0; c < 4; ++c)
#pragma unroll
    for (int g = 0; g < 4; ++g) acc[c][g] = 0.f;

  float4 pf0, pf1;
  GXLOAD(0)
  GXWRITE(xt0)
  GXLOAD(1)
  __syncthreads();

#pragma unroll 2
  for (int s = 0; s < 16; ++s) {     // 16 slabs of 64 k
    float* cur = (s & 1) ? xt1 : xt0;
    float* nxt = (s & 1) ? xt0 : xt1;
    if (s < 15) { GXWRITE(nxt) }     // data loaded during previous slab
    if (s < 14) { GXLOAD(s + 2) }    // issue next loads; hidden under compute
    GXCMP(cur)
    __syncthreads();
  }

  // cross-wave reduce (red overlays xt; all compute sealed by last barrier)
#pragma unroll
  for (int c = 0; c < 4; ++c)
#pragma unroll
    for (int g = 0; g < 4; ++g) red[(w * 64 + lane) * 17 + c * 4 + g] = acc[c][g];
  __syncthreads();

  if (tid < 256) {
    const int b = tid >> 2;
    const int c = tid & 3;
    const int h = hbase + c;
    float4 v;
    float* vp = &v.x;
#pragma unroll
    for (int g = 0; g < 4; ++g) {
      float s = bias[g * H_ + h];
#pragma unroll
      for (int ww = 0; ww < 8; ++ww) s += red[(ww * 64 + b) * 17 + c * 4 + g];
      vp[g] = s;
    }
    *(float4*)(gx + ((size_t)(blockIdx.x * 256 + blockIdx.y) * 64 + b) * 16 + c * 4) = v;
  }
}

// ---------------- persistent recurrence ----------------
// hv chunk prefetch: two named 32-reg arrays, fully unrolled (forces deep
// pipelining — R5's compiler chose 32 VGPRs and exposed all load latency).
#define RPF(HV, KB)                                                 \
  _Pragma("unroll") for (int j = 0; j < 32; ++j)                    \
      HV[j] = hin[((KB) + j) * 64 + lane];
#define RCMP(HV, KB)                                                \
  _Pragma("unroll") for (int j = 0; j < 32; ++j) {                  \
    const float* wp = wlds + ((KB) + j) * 16;                       \
    const float4 w0 = *(const float4*)(wp);                         \
    const float4 w1 = *(const float4*)(wp + 4);                     \
    const float4 w2 = *(const float4*)(wp + 8);                     \
    const float4 w3 = *(const float4*)(wp + 12);                    \
    const float hv = HV[j];                                         \
    FMA16(hv, w0, w1, w2, w3)                                       \
  }

__global__ __launch_bounds__(512, 2) void k_recur(
    const float* __restrict__ Wh,     // [1024][4096]
    const float* __restrict__ gx,     // [tc][256][64][16] (bias folded)
    float* __restrict__ hA,           // hT ping [1024][64]
    float* __restrict__ hB,           // hT pong [1024][64]
    float* __restrict__ c_state,      // [64][1024] in-place
    float* __restrict__ ys,           // [64][512][1024]
    unsigned* __restrict__ bar,       // 8 arrival cells + epoch (zeroed per launch)
    int t0, int tc) {
  extern __shared__ float smem[];
  float* wlds = smem;           // 16384 floats = 64 KB
  float* red = smem + 16384;    // 8704 floats = 34 KB

  const int tid = threadIdx.x;
  const int lane = tid & 63;
  const int w = tid >> 6;
  const int hbase = blockIdx.x * 4;

  // stage this block's Wh slice once: wlds[k*16 + g*4 + c]
  for (int idx = tid; idx < 4096; idx += 512) {
    const int k = idx >> 2;
    const int g = idx & 3;
    const float4 v = *(const float4*)(Wh + (size_t)k * NG_ + g * H_ + hbase);
    *(float4*)(wlds + k * 16 + g * 4) = v;
  }
  __syncthreads();

  const int k0 = w * 128;

  for (int tt = 0; tt < tc; ++tt) {
    const int t = t0 + tt;
    const float* __restrict__ hin = (t & 1) ? hB : hA;
    float* __restrict__ hout = (t & 1) ? hA : hB;

    float acc[4][4];
#pragma unroll
    for (int c = 0; c < 4; ++c)
#pragma unroll
      for (int g = 0; g < 4; ++g) acc[c][g] = 0.f;

    float hva[32], hvb[32];
    RPF(hva, k0)
    RPF(hvb, k0 + 32)
    RCMP(hva, k0)
    RPF(hva, k0 + 64)
    RCMP(hvb, k0 + 32)
    RPF(hvb, k0 + 96)
    RCMP(hva, k0 + 64)
    RCMP(hvb, k0 + 96)

#pragma unroll
    for (int c = 0; c < 4; ++c)
#pragma unroll
      for (int g = 0; g < 4; ++g) red[(w * 64 + lane) * 17 + c * 4 + g] = acc[c][g];
    __syncthreads();

    if (tid < 256) {
      const int b = tid >> 2;
      const int c = tid & 3;
      const int h = hbase + c;
      const float4 gxv =
          *(const float4*)(gx + ((size_t)(tt * 256 + blockIdx.x) * 64 + b) * 16 + c * 4);
      const float* gp = &gxv.x;
      float v[4];
#pragma unroll
      for (int g = 0; g < 4; ++g) {
        float s = gp[g];
#pragma unroll
        for (int ww = 0; ww < 8; ++ww) s += red[(ww * 64 + b) * 17 + c * 4 + g];
        v[g] = s;
      }
      const float cold = c_state[b * H_ + h];
      const float si = 1.f / (1.f + expf(-v[0]));
      const float sf = 1.f / (1.f + expf(-v[1]));
      const float gt = tanhf(v[2]);
      const float so = 1.f / (1.f + expf(-v[3]));
      const float cn = sf * cold + si * gt;
      const float hn = so * tanhf(cn);
      c_state[b * H_ + h] = cn;
      hout[h * 64 + b] = hn;
      ys[(size_t)b * (T_ * H_) + (size_t)t * H_ + h] = hn;
    }

    // ---- grid barrier: 8 spread arrival cells + epoch broadcast ----
    __syncthreads();
    if (tid == 0) {
      __threadfence();                                     // release writes
      __hip_atomic_fetch_add(&bar[(blockIdx.x & 7) << 5], 1u,
                             __ATOMIC_RELEASE, __HIP_MEMORY_SCOPE_AGENT);
      const unsigned tgt = (unsigned)(t + 1);
      if (blockIdx.x == 0) {
        unsigned s;
        do {
          s = 0;
#pragma unroll
          for (int i = 0; i < 8; ++i)
            s += __hip_atomic_load(&bar[i << 5], __ATOMIC_RELAXED,
                                   __HIP_MEMORY_SCOPE_AGENT);
          if (s < 256u * tgt) __builtin_amdgcn_s_sleep(1);
        } while (s < 256u * tgt);
        __threadfence();
        __hip_atomic_store(&bar[256], tgt, __ATOMIC_RELEASE,
                           __HIP_MEMORY_SCOPE_AGENT);
      } else {
        while (__hip_atomic_load(&bar[256], __ATOMIC_RELAXED,
                                 __HIP_MEMORY_SCOPE_AGENT) < tgt)
          __builtin_amdgcn_s_sleep(1);
      }
      __threadfence();                                     // acquire
    }
    __syncthreads();
  }
}

// ---------------- fallback: fused step (tiny ws) ----------------
__global__ __launch_bounds__(512, 2) void k_lstm_step_fused(
    const float* __restrict__ xsrc, const float* __restrict__ Wi,
    const float* __restrict__ Wh, const float* __restrict__ bias,
    const float* __restrict__ hT_in, float* __restrict__ hT_out,
    float* __restrict__ c_state, float* __restrict__ ys_t) {
  __shared__ float red[8 * 64 * 17];
  const int tid = threadIdx.x;
  const int lane = tid & 63;
  const int w = tid >> 6;
  const int hbase = blockIdx.x * 4;
  float acc[4][4];
#pragma unroll
  for (int c = 0; c < 4; ++c)
#pragma unroll
    for (int g = 0; g < 4; ++g) acc[c][g] = 0.f;
  const int k0 = w * 128;
#pragma unroll 2
  for (int k = k0; k < k0 + 128; ++k) {
    const float hv = hT_in[k * 64 + lane];
    const float xv = xsrc[(size_t)lane * (T_ * D_) + k];
    const float4 wh0 = *(const float4*)(Wh + (size_t)k * NG_ + 0 * H_ + hbase);
    const float4 wh1 = *(const float4*)(Wh + (size_t)k * NG_ + 1 * H_ + hbase);
    const float4 wh2 = *(const float4*)(Wh + (size_t)k * NG_ + 2 * H_ + hbase);
    const float4 wh3 = *(const float4*)(Wh + (size_t)k * NG_ + 3 * H_ + hbase);
    FMA16(hv, wh0, wh1, wh2, wh3)
    const float4 wi0 = *(const float4*)(Wi + (size_t)k * NG_ + 0 * H_ + hbase);
    const float4 wi1 = *(const float4*)(Wi + (size_t)k * NG_ + 1 * H_ + hbase);
    const float4 wi2 = *(const float4*)(Wi + (size_t)k * NG_ + 2 * H_ + hbase);
    const float4 wi3 = *(const float4*)(Wi + (size_t)k * NG_ + 3 * H_ + hbase);
    FMA16(xv, wi0, wi1, wi2, wi3)
  }
#pragma unroll
  for (int c = 0; c < 4; ++c)
#pragma unroll
    for (int g = 0; g < 4; ++g) red[(w * 64 + lane) * 17 + c * 4 + g] = acc[c][g];
  __syncthreads();
  if (tid < 256) {
    const int b = tid >> 2;
    const int c = tid & 3;
    const int h = hbase + c;
    float v[4];
#pragma unroll
    for (int g = 0; g < 4; ++g) {
      float s = bias[g * H_ + h];
#pragma unroll
      for (int ww = 0; ww < 8; ++ww) s += red[(ww * 64 + b) * 17 + c * 4 + g];
      v[g] = s;
    }
    const float cold = c_state[b * H_ + h];
    const float si = 1.f / (1.f + expf(-v[0]));
    const float sf = 1.f / (1.f + expf(-v[1]));
    const float gt = tanhf(v[2]);
    const float so = 1.f / (1.f + expf(-v[3]));
    const float cn = sf * cold + si * gt;
    const float hn = so * tanhf(cn);
    c_state[b * H_ + h] = cn;
    hT_out[h * 64 + b] = hn;
    ys_t[(size_t)b * (T_ * H_) + h] = hn;
  }
}

extern "C" void kernel_launch(void* const* d_in, const int* in_sizes, int n_in,
                              void* d_out, int out_size, void* d_ws, size_t ws_size,
                              hipStream_t stream) {
  const float* c0   = (const float*)d_in[0];
  const float* h0   = (const float*)d_in[1];
  const float* x    = (const float*)d_in[2];
  const float* Wi   = (const float*)d_in[3];
  const float* Wh   = (const float*)d_in[4];
  const float* bias = (const float*)d_in[5];

  float* out     = (float*)d_out;
  float* c_state = out;
  float* h_final = out + B_ * H_;
  float* ys      = out + 2 * B_ * H_;

  const size_t hbytes = (size_t)B_ * H_ * sizeof(float);
  unsigned* bar = (unsigned*)d_ws;                         // 4 KB reserved
  float* hA = (float*)((char*)d_ws + 4096);
  float* hB = hA + B_ * H_;
  float* gxbuf = hB + B_ * H_;

  const size_t slice = (size_t)256 * 64 * 16 * sizeof(float);  // 1 MB per t
  size_t fixed = 4096 + 2 * hbytes;
  size_t avail = (ws_size > fixed) ? ws_size - fixed : 0;
  int Tc = (int)(avail / slice);
  if (Tc > T_) Tc = T_;

  hipMemsetAsync(bar, 0, 4096, stream);   // reset barrier cells every launch
  hipMemcpyAsync(c_state, c0, hbytes, hipMemcpyDeviceToDevice, stream);
  k_trans_h_fwd<<<B_ * H_ / 256, 256, 0, stream>>>(h0, hA);

  const unsigned smem_recur = (16384 + 8704) * sizeof(float);  // 100352 B

  if (Tc >= 1) {
    for (int t0 = 0; t0 < T_; t0 += Tc) {
      const int tc = (T_ - t0 < Tc) ? (T_ - t0) : Tc;
      dim3 gg(tc, 256);   // x = t (consecutive blocks share a Wi slice), y = cb
      k_gx<<<gg, 512, 0, stream>>>(x, Wi, bias, gxbuf, t0);
      int t0v = t0, tcv = tc;
      void* args[] = {(void*)&Wh,  (void*)&gxbuf,   (void*)&hA,
                      (void*)&hB,  (void*)&c_state, (void*)&ys,
                      (void*)&bar, (void*)&t0v,     (void*)&tcv};
      hipLaunchCooperativeKernel((void*)k_recur, dim3(NBLK), dim3(512), args,
                                 smem_recur, stream);
    }
  } else {
    for (int t = 0; t < T_; ++t) {
      const float* hin = (t & 1) ? hB : hA;
      float* hout      = (t & 1) ? hA : hB;
      k_lstm_step_fused<<<256, 512, 0, stream>>>(
          x + (size_t)t * D_, Wi, Wh, bias, hin, hout, c_state,
          ys + (size_t)t * H_);
    }
  }
  k_trans_h_back<<<B_ * H_ / 256, 256, 0, stream>>>(hA, h_final);
}

// Round 7
// 22936.223 us; speedup vs baseline: 2.6441x; 1.5527x over previous
//
#include <hip/hip_runtime.h>

#define B_ 64
#define T_ 512
#define D_ 1024
#define H_ 1024
#define NG_ 4096   // 4*H
#define NBLK 256

// acc[i][j] += Q[i] * V[j]  (outer product of two float4s, 16 FMAs)
#define FMA44(Q, V)                              \
  acc[0][0] = fmaf((Q).x, (V).x, acc[0][0]);     \
  acc[0][1] = fmaf((Q).x, (V).y, acc[0][1]);     \
  acc[0][2] = fmaf((Q).x, (V).z, acc[0][2]);     \
  acc[0][3] = fmaf((Q).x, (V).w, acc[0][3]);     \
  acc[1][0] = fmaf((Q).y, (V).x, acc[1][0]);     \
  acc[1][1] = fmaf((Q).y, (V).y, acc[1][1]);     \
  acc[1][2] = fmaf((Q).y, (V).z, acc[1][2]);     \
  acc[1][3] = fmaf((Q).y, (V).w, acc[1][3]);     \
  acc[2][0] = fmaf((Q).z, (V).x, acc[2][0]);     \
  acc[2][1] = fmaf((Q).z, (V).y, acc[2][1]);     \
  acc[2][2] = fmaf((Q).z, (V).z, acc[2][2]);     \
  acc[2][3] = fmaf((Q).z, (V).w, acc[2][3]);     \
  acc[3][0] = fmaf((Q).w, (V).x, acc[3][0]);     \
  acc[3][1] = fmaf((Q).w, (V).y, acc[3][1]);     \
  acc[3][2] = fmaf((Q).w, (V).z, acc[3][2]);     \
  acc[3][3] = fmaf((Q).w, (V).w, acc[3][3]);

// ---------------- h transpose helpers ----------------
__global__ __launch_bounds__(256) void k_trans_h_fwd(const float* __restrict__ h,
                                                     float* __restrict__ hT) {
  int idx = blockIdx.x * 256 + threadIdx.x;  // idx = k*64 + b
  int b = idx & 63;
  int k = idx >> 6;
  hT[idx] = h[b * H_ + k];
}

__global__ __launch_bounds__(256) void k_trans_h_back(const float* __restrict__ hT,
                                                      float* __restrict__ h) {
  int idx = blockIdx.x * 256 + threadIdx.x;  // idx = b*1024 + k
  int k = idx & (H_ - 1);
  int b = idx >> 10;
  h[idx] = hT[k * 64 + b];
}

// ---------------- Gx = x@Wi + bias ----------------
// Grid (256 cb, tc): consecutive blocks share x[t] (L2-hit); XCD = cb%8 pins a
// stable 2MB Wi slice-set per XCD (L2-resident across all t).
// Lane = (bg 0..15) x (cg 0..3): thread covers b = bg*4..+3, gate g = cg,
// h-cols c = 0..3. Per k per wave: 1 global b128 (Wi[k][g*H+hbase..+3]) +
// 1 LDS b128 (x[k][bg*4..+3]) + 16 FMA -> VALU-bound.
#define GXLOAD(S)                                                   \
  { pf0 = *(const float4*)(xrow + (S) * 64 + c4);                   \
    pf1 = *(const float4*)(xrow + (S) * 64 + c4 + 32); }
#define GXWRITE(BUF)                                                \
  { (BUF)[(c4 + 0) * 68 + bwr] = pf0.x;                             \
    (BUF)[(c4 + 1) * 68 + bwr] = pf0.y;                             \
    (BUF)[(c4 + 2) * 68 + bwr] = pf0.z;                             \
    (BUF)[(c4 + 3) * 68 + bwr] = pf0.w;                             \
    (BUF)[(c4 + 32) * 68 + bwr] = pf1.x;                            \
    (BUF)[(c4 + 33) * 68 + bwr] = pf1.y;                            \
    (BUF)[(c4 + 34) * 68 + bwr] = pf1.z;                            \
    (BUF)[(c4 + 35) * 68 + bwr] = pf1.w; }
#define GXCMP(BUF, S)                                               \
  { float4 wv[8];                                                   \
    _Pragma("unroll") for (int j = 0; j < 8; ++j)                   \
        wv[j] = *(const float4*)(Wi + (size_t)((S) * 64 + (w << 3) + j) * NG_ + \
                                 (size_t)cg * H_ + hbase);          \
    _Pragma("unroll") for (int j = 0; j < 8; ++j) {                 \
      const float4 xq = *(const float4*)((BUF) + ((w << 3) + j) * 68 + bg4); \
      FMA44(xq, wv[j])                                              \
    } }

__global__ __launch_bounds__(512, 2) void k_gx(
    const float* __restrict__ x,     // [64][512][1024]
    const float* __restrict__ Wi,    // [1024][4096]
    const float* __restrict__ bias,  // [4096]
    float* __restrict__ gx,          // [Tc][256][64][16], i = c*4+g
    int t0) {
  __shared__ float smem[8704];       // xt0[4352] | xt1[4352]; red overlays
  float* xt0 = smem;
  float* xt1 = smem + 4352;
  float* red = smem;

  const int tid = threadIdx.x;
  const int lane = tid & 63;
  const int w = tid >> 6;
  const int bg = lane & 15;
  const int cg = lane >> 4;          // this thread's gate
  const int bg4 = bg * 4;
  const int hbase = blockIdx.x * 4;
  const int t = t0 + blockIdx.y;

  const float* xrow = x + (size_t)(tid >> 3) * (T_ * D_) + (size_t)t * D_;
  const int c4 = (tid & 7) * 4;
  const int bwr = tid >> 3;          // write-side b row

  float acc[4][4];
#pragma unroll
  for (int i = 0; i < 4; ++i)
#pragma unroll
    for (int j = 0; j < 4; ++j) acc[i][j] = 0.f;

  float4 pf0, pf1;
  GXLOAD(0)
  GXWRITE(xt0)
  GXLOAD(1)
  __syncthreads();

#pragma unroll 2
  for (int s = 0; s < 16; ++s) {     // 16 slabs of 64 k
    float* cur = (s & 1) ? xt1 : xt0;
    float* nxt = (s & 1) ? xt0 : xt1;
    if (s < 15) { GXWRITE(nxt) }
    if (s < 14) { GXLOAD(s + 2) }
    GXCMP(cur, s)
    __syncthreads();
  }

  // cross-wave reduce; i = bsub*4 + c
#pragma unroll
  for (int i = 0; i < 4; ++i)
#pragma unroll
    for (int j = 0; j < 4; ++j) red[(w * 64 + lane) * 17 + i * 4 + j] = acc[i][j];
  __syncthreads();

  if (tid < 256) {
    const int b = tid >> 2;
    const int c = tid & 3;
    const int h = hbase + c;
    float4 v;
    float* vp = &v.x;
#pragma unroll
    for (int g = 0; g < 4; ++g) {
      float s = bias[g * H_ + h];
#pragma unroll
      for (int ww = 0; ww < 8; ++ww)
        s += red[(ww * 64 + g * 16 + (b >> 2)) * 17 + (b & 3) * 4 + c];
      vp[g] = s;
    }
    *(float4*)(gx + ((size_t)(blockIdx.y * 256 + blockIdx.x) * 64 + b) * 16 + c * 4) = v;
  }
}

// ---------------- persistent recurrence ----------------
// Lane = (bg 0..15) x (cg 0..3): thread covers b = bg*4..+3, h-col c = cg,
// gates g = 0..3. Per k per wave: 1 LDS b128 (wlds[k][cg*4..+3], 16-lane
// broadcast, conflict-free) + 1 global dwordx4 (hT[k][bg*4..+3]) + 16 FMA.
// Weight-LDS traffic drops 4x vs R6 (was 4 broadcast b128/k = LDS-issue-bound).
#define RPF16(HV, KB)                                               \
  _Pragma("unroll") for (int j = 0; j < 16; ++j)                    \
      HV[j] = *(const float4*)(hin + (size_t)((KB) + j) * 64 + bg4);
#define RCMP16(HV, KB)                                              \
  _Pragma("unroll") for (int j = 0; j < 16; ++j) {                  \
    const float4 wv = *(const float4*)(wlds + ((KB) + j) * 16 + cg4); \
    FMA44(HV[j], wv)                                                \
  }

__global__ __launch_bounds__(512, 2) void k_recur(
    const float* __restrict__ Wh,     // [1024][4096]
    const float* __restrict__ gx,     // [tc][256][64][16] (bias folded)
    float* __restrict__ hA,           // hT ping [1024][64]
    float* __restrict__ hB,           // hT pong [1024][64]
    float* __restrict__ c_state,      // [64][1024] in-place
    float* __restrict__ ys,           // [64][512][1024]
    unsigned* __restrict__ bar,       // 8 arrival cells + epoch
    int t0, int tc) {
  extern __shared__ float smem[];
  float* wlds = smem;           // [1024][16], j = c*4 + g
  float* red = smem + 16384;

  const int tid = threadIdx.x;
  const int lane = tid & 63;
  const int w = tid >> 6;
  const int bg = lane & 15;
  const int cg = lane >> 4;          // this thread's h-col
  const int bg4 = bg * 4;
  const int cg4 = cg * 4;
  const int hbase = blockIdx.x * 4;

  // stage Wh slice once: wlds[k*16 + c*4 + g] = Wh[k][g*H + hbase + c]
  for (int idx = tid; idx < 4096; idx += 512) {
    const int k = idx >> 2;
    const int g = idx & 3;
    const float4 v = *(const float4*)(Wh + (size_t)k * NG_ + g * H_ + hbase);
    wlds[k * 16 + 0 + g] = v.x;
    wlds[k * 16 + 4 + g] = v.y;
    wlds[k * 16 + 8 + g] = v.z;
    wlds[k * 16 + 12 + g] = v.w;
  }
  __syncthreads();

  const int k0 = w * 128;

  for (int tt = 0; tt < tc; ++tt) {
    const int t = t0 + tt;
    const float* __restrict__ hin = (t & 1) ? hB : hA;
    float* __restrict__ hout = (t & 1) ? hA : hB;

    float acc[4][4];
#pragma unroll
    for (int i = 0; i < 4; ++i)
#pragma unroll
      for (int j = 0; j < 4; ++j) acc[i][j] = 0.f;

    // hoist epilogue loads (independent of the GEMV)
    float4 gxv;
    float cold;
    if (tid < 256) {
      gxv = *(const float4*)(gx +
          ((size_t)(tt * 256 + blockIdx.x) * 64 + (tid >> 2)) * 16 + (tid & 3) * 4);
      cold = c_state[(tid >> 2) * H_ + hbase + (tid & 3)];
    }

    float4 ha[16], hb[16];
    RPF16(ha, k0)
    RPF16(hb, k0 + 16)
    RCMP16(ha, k0)       RPF16(ha, k0 + 32)
    RCMP16(hb, k0 + 16)  RPF16(hb, k0 + 48)
    RCMP16(ha, k0 + 32)  RPF16(ha, k0 + 64)
    RCMP16(hb, k0 + 48)  RPF16(hb, k0 + 80)
    RCMP16(ha, k0 + 64)  RPF16(ha, k0 + 96)
    RCMP16(hb, k0 + 80)  RPF16(hb, k0 + 112)
    RCMP16(ha, k0 + 96)
    RCMP16(hb, k0 + 112)

    // red[w][lane][bsub*4 + g]
#pragma unroll
    for (int i = 0; i < 4; ++i)
#pragma unroll
      for (int j = 0; j < 4; ++j) red[(w * 64 + lane) * 17 + i * 4 + j] = acc[i][j];
    __syncthreads();

    if (tid < 256) {
      const int b = tid >> 2;
      const int c = tid & 3;
      const int h = hbase + c;
      const float* gp = &gxv.x;
      float v[4];
#pragma unroll
      for (int g = 0; g < 4; ++g) {
        float s = gp[g];
#pragma unroll
        for (int ww = 0; ww < 8; ++ww)
          s += red[(ww * 64 + c * 16 + (b >> 2)) * 17 + (b & 3) * 4 + g];
        v[g] = s;
      }
      const float si = 1.f / (1.f + expf(-v[0]));
      const float sf = 1.f / (1.f + expf(-v[1]));
      const float gt = tanhf(v[2]);
      const float so = 1.f / (1.f + expf(-v[3]));
      const float cn = sf * cold + si * gt;
      const float hn = so * tanhf(cn);
      c_state[b * H_ + h] = cn;
      hout[h * 64 + b] = hn;
      ys[(size_t)b * (T_ * H_) + (size_t)t * H_ + h] = hn;
    }

    // ---- grid barrier: 8 spread arrival cells + epoch broadcast ----
    __syncthreads();
    if (tid == 0) {
      __threadfence();
      __hip_atomic_fetch_add(&bar[(blockIdx.x & 7) << 5], 1u,
                             __ATOMIC_RELEASE, __HIP_MEMORY_SCOPE_AGENT);
      const unsigned tgt = (unsigned)(t + 1);
      if (blockIdx.x == 0) {
        unsigned s;
        do {
          s = 0;
#pragma unroll
          for (int i = 0; i < 8; ++i)
            s += __hip_atomic_load(&bar[i << 5], __ATOMIC_RELAXED,
                                   __HIP_MEMORY_SCOPE_AGENT);
          if (s < 256u * tgt) __builtin_amdgcn_s_sleep(1);
        } while (s < 256u * tgt);
        __threadfence();
        __hip_atomic_store(&bar[256], tgt, __ATOMIC_RELEASE,
                           __HIP_MEMORY_SCOPE_AGENT);
      } else {
        while (__hip_atomic_load(&bar[256], __ATOMIC_RELAXED,
                                 __HIP_MEMORY_SCOPE_AGENT) < tgt)
          __builtin_amdgcn_s_sleep(1);
      }
      __threadfence();
    }
    __syncthreads();
  }
}

// ---------------- fallback: fused step (tiny ws) ----------------
#define FMA16F(V, W0, W1, W2, W3)               \
  acc[0][0] = fmaf((V), (W0).x, acc[0][0]);     \
  acc[1][0] = fmaf((V), (W0).y, acc[1][0]);     \
  acc[2][0] = fmaf((V), (W0).z, acc[2][0]);     \
  acc[3][0] = fmaf((V), (W0).w, acc[3][0]);     \
  acc[0][1] = fmaf((V), (W1).x, acc[0][1]);     \
  acc[1][1] = fmaf((V), (W1).y, acc[1][1]);     \
  acc[2][1] = fmaf((V), (W1).z, acc[2][1]);     \
  acc[3][1] = fmaf((V), (W1).w, acc[3][1]);     \
  acc[0][2] = fmaf((V), (W2).x, acc[0][2]);     \
  acc[1][2] = fmaf((V), (W2).y, acc[1][2]);     \
  acc[2][2] = fmaf((V), (W2).z, acc[2][2]);     \
  acc[3][2] = fmaf((V), (W2).w, acc[3][2]);     \
  acc[0][3] = fmaf((V), (W3).x, acc[0][3]);     \
  acc[1][3] = fmaf((V), (W3).y, acc[1][3]);     \
  acc[2][3] = fmaf((V), (W3).z, acc[2][3]);     \
  acc[3][3] = fmaf((V), (W3).w, acc[3][3]);

__global__ __launch_bounds__(512, 2) void k_lstm_step_fused(
    const float* __restrict__ xsrc, const float* __restrict__ Wi,
    const float* __restrict__ Wh, const float* __restrict__ bias,
    const float* __restrict__ hT_in, float* __restrict__ hT_out,
    float* __restrict__ c_state, float* __restrict__ ys_t) {
  __shared__ float red[8 * 64 * 17];
  const int tid = threadIdx.x;
  const int lane = tid & 63;
  const int w = tid >> 6;
  const int hbase = blockIdx.x * 4;
  float acc[4][4];
#pragma unroll
  for (int c = 0; c < 4; ++c)
#pragma unroll
    for (int g = 0; g < 4; ++g) acc[c][g] = 0.f;
  const int k0 = w * 128;
#pragma unroll 2
  for (int k = k0; k < k0 + 128; ++k) {
    const float hv = hT_in[k * 64 + lane];
    const float xv = xsrc[(size_t)lane * (T_ * D_) + k];
    const float4 wh0 = *(const float4*)(Wh + (size_t)k * NG_ + 0 * H_ + hbase);
    const float4 wh1 = *(const float4*)(Wh + (size_t)k * NG_ + 1 * H_ + hbase);
    const float4 wh2 = *(const float4*)(Wh + (size_t)k * NG_ + 2 * H_ + hbase);
    const float4 wh3 = *(const float4*)(Wh + (size_t)k * NG_ + 3 * H_ + hbase);
    FMA16F(hv, wh0, wh1, wh2, wh3)
    const float4 wi0 = *(const float4*)(Wi + (size_t)k * NG_ + 0 * H_ + hbase);
    const float4 wi1 = *(const float4*)(Wi + (size_t)k * NG_ + 1 * H_ + hbase);
    const float4 wi2 = *(const float4*)(Wi + (size_t)k * NG_ + 2 * H_ + hbase);
    const float4 wi3 = *(const float4*)(Wi + (size_t)k * NG_ + 3 * H_ + hbase);
    FMA16F(xv, wi0, wi1, wi2, wi3)
  }
#pragma unroll
  for (int c = 0; c < 4; ++c)
#pragma unroll
    for (int g = 0; g < 4; ++g) red[(w * 64 + lane) * 17 + c * 4 + g] = acc[c][g];
  __syncthreads();
  if (tid < 256) {
    const int b = tid >> 2;
    const int c = tid & 3;
    const int h = hbase + c;
    float v[4];
#pragma unroll
    for (int g = 0; g < 4; ++g) {
      float s = bias[g * H_ + h];
#pragma unroll
      for (int ww = 0; ww < 8; ++ww) s += red[(ww * 64 + b) * 17 + c * 4 + g];
      v[g] = s;
    }
    const float cold = c_state[b * H_ + h];
    const float si = 1.f / (1.f + expf(-v[0]));
    const float sf = 1.f / (1.f + expf(-v[1]));
    const float gt = tanhf(v[2]);
    const float so = 1.f / (1.f + expf(-v[3]));
    const float cn = sf * cold + si * gt;
    const float hn = so * tanhf(cn);
    c_state[b * H_ + h] = cn;
    hT_out[h * 64 + b] = hn;
    ys_t[(size_t)b * (T_ * H_) + h] = hn;
  }
}

extern "C" void kernel_launch(void* const* d_in, const int* in_sizes, int n_in,
                              void* d_out, int out_size, void* d_ws, size_t ws_size,
                              hipStream_t stream) {
  const float* c0   = (const float*)d_in[0];
  const float* h0   = (const float*)d_in[1];
  const float* x    = (const float*)d_in[2];
  const float* Wi   = (const float*)d_in[3];
  const float* Wh   = (const float*)d_in[4];
  const float* bias = (const float*)d_in[5];

  float* out     = (float*)d_out;
  float* c_state = out;
  float* h_final = out + B_ * H_;
  float* ys      = out + 2 * B_ * H_;

  const size_t hbytes = (size_t)B_ * H_ * sizeof(float);
  unsigned* bar = (unsigned*)d_ws;                         // 4 KB reserved
  float* hA = (float*)((char*)d_ws + 4096);
  float* hB = hA + B_ * H_;
  float* gxbuf = hB + B_ * H_;

  const size_t slice = (size_t)256 * 64 * 16 * sizeof(float);  // 1 MB per t
  size_t fixed = 4096 + 2 * hbytes;
  size_t avail = (ws_size > fixed) ? ws_size - fixed : 0;
  int Tc = (int)(avail / slice);
  if (Tc > T_) Tc = T_;

  hipMemsetAsync(bar, 0, 4096, stream);
  hipMemcpyAsync(c_state, c0, hbytes, hipMemcpyDeviceToDevice, stream);
  k_trans_h_fwd<<<B_ * H_ / 256, 256, 0, stream>>>(h0, hA);

  const unsigned smem_recur = (16384 + 8704) * sizeof(float);  // 100352 B

  if (Tc >= 1) {
    for (int t0 = 0; t0 < T_; t0 += Tc) {
      const int tc = (T_ - t0 < Tc) ? (T_ - t0) : Tc;
      dim3 gg(256, tc);   // x = cb, y = t: consecutive blocks share x[t]
      k_gx<<<gg, 512, 0, stream>>>(x, Wi, bias, gxbuf, t0);
      int t0v = t0, tcv = tc;
      void* args[] = {(void*)&Wh,  (void*)&gxbuf,   (void*)&hA,
                      (void*)&hB,  (void*)&c_state, (void*)&ys,
                      (void*)&bar, (void*)&t0v,     (void*)&tcv};
      hipLaunchCooperativeKernel((void*)k_recur, dim3(NBLK), dim3(512), args,
                                 smem_recur, stream);
    }
  } else {
    for (int t = 0; t < T_; ++t) {
      const float* hin = (t & 1) ? hB : hA;
      float* hout      = (t & 1) ? hA : hB;
      k_lstm_step_fused<<<256, 512, 0, stream>>>(
          x + (size_t)t * D_, Wi, Wh, bias, hin, hout, c_state,
          ys + (size_t)t * H_);
    }
  }
  k_trans_h_back<<<B_ * H_ / 256, 256, 0, stream>>>(hA, h_final);
}